// Round 4
// baseline (273.032 us; speedup 1.0000x reference)
//
#include <hip/hip_runtime.h>
#include <hip/hip_bf16.h>
#include <math.h>

typedef _Float16 f16;
typedef __attribute__((ext_vector_type(8))) _Float16 f16x8;
typedef __attribute__((ext_vector_type(16))) float f32x16;

// Problem constants
#define DIMS 256
#define NCODE 1024
#define NPTS 65536          // 64 * 32 * 32

// d_out layout (floats): [0]=loss, [1..16777217)=quantized NCHW (2^24 elems),
// [16777217]=perplexity, [16777218..16842754)=idx as float (65536)
#define OUT_Q_OFF 1
#define OUT_PERP_OFF 16777217
#define OUT_IDX_OFF 16777218

// E hi/lo f16 planes parked inside the (later overwritten) quantized out region.
#define EHI_F32_OFF 4
#define ELO_F32_OFF (4 + 131072)

#define ESTRIDE 264         // f16 per padded LDS row (528 B) — 0 bank conflicts measured
#define XSTRIDE 132         // fp32 per padded LDS row for X transpose chunks
#define PLANE_BYTES 16896   // 32 rows * ESTRIDE * 2B

// ---------------------------------------------------------------------------
// Split E into f16 hi/lo planes. 256 blocks x 256 thr, 4 elems/thread.
__global__ __launch_bounds__(256) void k_esplit(const float* __restrict__ ew,
                                                f16* __restrict__ ehi,
                                                f16* __restrict__ elo) {
    int g = blockIdx.x * 256 + threadIdx.x;       // 0..65535
    float4 v = *reinterpret_cast<const float4*>(ew + (size_t)g * 4);
    float vv[4] = {v.x, v.y, v.z, v.w};
    __align__(8) f16 hh[4];
    __align__(8) f16 ll[4];
    #pragma unroll
    for (int e = 0; e < 4; ++e) {
        f16 h = (f16)vv[e];
        hh[e] = h;
        ll[e] = (f16)(vv[e] - (float)h);
    }
    *reinterpret_cast<float2*>(ehi + (size_t)g * 4) = *reinterpret_cast<float2*>(hh);
    *reinterpret_cast<float2*>(elo + (size_t)g * 4) = *reinterpret_cast<float2*>(ll);
}

// ---------------------------------------------------------------------------
// ||e_k||^2 per codeword (fp32 exact). One wave per row.
__global__ __launch_bounds__(64) void k_enorm(const float* __restrict__ ew,
                                              float* __restrict__ enorm) {
    int row = blockIdx.x;
    int l = threadIdx.x;
    float4 v = *reinterpret_cast<const float4*>(ew + row * DIMS + l * 4);
    float s = v.x * v.x + v.y * v.y + v.z * v.z + v.w * v.w;
    #pragma unroll
    for (int off = 32; off > 0; off >>= 1) s += __shfl_down(s, off);
    if (l == 0) enorm[row] = s;
}

// ---------------------------------------------------------------------------
// MFMA argmin with double-buffered E + async-stage-split pipeline (1 barrier/round).
// Block = 4 waves x 32 points = 128 points, grid = 512.
__global__ __launch_bounds__(256, 2) void k_argmin_mfma(const float* __restrict__ x,
                                                        const f16* __restrict__ ehi,
                                                        const f16* __restrict__ elo,
                                                        const float* __restrict__ enorm,
                                                        int* __restrict__ out_idx) {
    __shared__ __align__(16) char smem[2 * 2 * PLANE_BYTES];   // [buf][plane] 67584 B
    __shared__ float enorm_lds[NCODE];
    float* Xs = (float*)smem;                   // phase 1: [64 dims][XSTRIDE] fp32 (33792 B)
    #define BUFP(b, pl) ((f16*)(smem + (((b) * 2) + (pl)) * PLANE_BYTES))

    const int t = threadIdx.x;
    const int wave = t >> 6;
    const int lane = t & 63;
    const int lrow = lane & 31;
    const int lhalf = lane >> 5;

    const int blk = blockIdx.x;                 // 0..511
    const int b = blk >> 3;
    const int hw0 = (blk & 7) << 7;
    const float* xb = x + (size_t)b * (DIMS * 1024) + hw0;

    // stage enorm into LDS (covered by barriers below, before first use)
    #pragma unroll
    for (int i = 0; i < 4; ++i) enorm_lds[t + 256 * i] = enorm[t + 256 * i];

    // ---- Phase 1: build split-f16 A fragments for this wave's 32 points ----
    f16x8 ahi[16], alo[16];
    #pragma unroll
    for (int dc = 0; dc < 4; ++dc) {
        __syncthreads();
        #pragma unroll
        for (int i = 0; i < 8; ++i) {
            int d = (t >> 5) + 8 * i;           // 0..63
            int p4 = (t & 31) * 4;              // 0..124
            float4 v = *reinterpret_cast<const float4*>(xb + (size_t)(dc * 64 + d) * 1024 + p4);
            *reinterpret_cast<float4*>(&Xs[d * XSTRIDE + p4]) = v;
        }
        __syncthreads();
        int p = wave * 32 + lrow;
        #pragma unroll
        for (int kcl = 0; kcl < 4; ++kcl) {
            f16x8 h, l;
            #pragma unroll
            for (int e = 0; e < 8; ++e) {
                float xv = Xs[(kcl * 16 + lhalf * 8 + e) * XSTRIDE + p];
                f16 hi = (f16)xv;
                h[e] = hi;
                l[e] = (f16)(xv - (float)hi);
            }
            ahi[dc * 4 + kcl] = h;
            alo[dc * 4 + kcl] = l;
        }
    }

    // ---- Prologue: stage round 0 into buffer 0 ----
    {
        float4 vh[4], vl[4];
        #pragma unroll
        for (int j = 0; j < 4; ++j) {
            int q = j * 256 + t;                // 0..1023
            int row = q >> 5;
            int cc = q & 31;
            vh[j] = *reinterpret_cast<const float4*>(ehi + (size_t)row * DIMS + cc * 8);
            vl[j] = *reinterpret_cast<const float4*>(elo + (size_t)row * DIMS + cc * 8);
        }
        __syncthreads();   // all waves done reading Xs
        f16* H = BUFP(0, 0);
        f16* L = BUFP(0, 1);
        #pragma unroll
        for (int j = 0; j < 4; ++j) {
            int q = j * 256 + t;
            int row = q >> 5;
            int cc = q & 31;
            *reinterpret_cast<float4*>(H + row * ESTRIDE + cc * 8) = vh[j];
            *reinterpret_cast<float4*>(L + row * ESTRIDE + cc * 8) = vl[j];
        }
        __syncthreads();
    }

    // ---- Main loop: 32 rounds of 32 codes, 1 barrier per round ----
    float bestv[16];
    int besti[16];
    #pragma unroll
    for (int r = 0; r < 16; ++r) { bestv[r] = 3.4e38f; besti[r] = 0; }

    for (int rd = 0; rd < 32; ++rd) {
        const int cur = rd & 1;
        const bool pf = (rd + 1 < 32);

        // issue next round's global loads early (latency hides under compute)
        float4 vh[4], vl[4];
        if (pf) {
            const int code0n = (rd + 1) * 32;
            #pragma unroll
            for (int j = 0; j < 4; ++j) {
                int q = j * 256 + t;
                int row = q >> 5;
                int cc = q & 31;
                vh[j] = *reinterpret_cast<const float4*>(ehi + (size_t)(code0n + row) * DIMS + cc * 8);
                vl[j] = *reinterpret_cast<const float4*>(elo + (size_t)(code0n + row) * DIMS + cc * 8);
            }
        }

        // compute current buffer
        const f16* EH = BUFP(cur, 0);
        const f16* EL = BUFP(cur, 1);
        f32x16 acc;
        #pragma unroll
        for (int r = 0; r < 16; ++r) acc[r] = 0.0f;

        #pragma unroll
        for (int kc = 0; kc < 16; ++kc) {
            f16x8 bh = *reinterpret_cast<const f16x8*>(EH + lrow * ESTRIDE + (kc * 2 + lhalf) * 8);
            f16x8 bl = *reinterpret_cast<const f16x8*>(EL + lrow * ESTRIDE + (kc * 2 + lhalf) * 8);
            acc = __builtin_amdgcn_mfma_f32_32x32x16_f16(ahi[kc], bh, acc, 0, 0, 0);
            acc = __builtin_amdgcn_mfma_f32_32x32x16_f16(ahi[kc], bl, acc, 0, 0, 0);
            acc = __builtin_amdgcn_mfma_f32_32x32x16_f16(alo[kc], bh, acc, 0, 0, 0);
        }

        // argmin update: s = ||e||^2 - 2*dot (||x||^2 dropped, constant per point)
        const int code0 = rd * 32;
        float en = enorm_lds[code0 + lrow];
        int cw = code0 + lrow;
        #pragma unroll
        for (int r = 0; r < 16; ++r) {
            float s = fmaf(-2.0f, acc[r], en);
            if (s < bestv[r]) { bestv[r] = s; besti[r] = cw; }   // strict <: lowest code wins
        }

        // write staged regs into the other buffer (nobody reads it until after barrier)
        if (pf) {
            f16* H = BUFP(cur ^ 1, 0);
            f16* L = BUFP(cur ^ 1, 1);
            #pragma unroll
            for (int j = 0; j < 4; ++j) {
                int q = j * 256 + t;
                int row = q >> 5;
                int cc = q & 31;
                *reinterpret_cast<float4*>(H + row * ESTRIDE + cc * 8) = vh[j];
                *reinterpret_cast<float4*>(L + row * ESTRIDE + cc * 8) = vl[j];
            }
        }
        __syncthreads();
    }

    // ---- cross-lane argmin reduce over the 32 codes dimension (lrow) ----
    #pragma unroll
    for (int off = 1; off <= 16; off <<= 1) {
        #pragma unroll
        for (int r = 0; r < 16; ++r) {
            float ov = __shfl_xor(bestv[r], off);
            int oi = __shfl_xor(besti[r], off);
            if (ov < bestv[r] || (ov == bestv[r] && oi < besti[r])) {
                bestv[r] = ov;
                besti[r] = oi;
            }
        }
    }
    if (lrow == 0) {
        #pragma unroll
        for (int r = 0; r < 16; ++r) {
            int row = (r & 3) + 8 * (r >> 2) + 4 * lhalf;   // C/D row mapping
            out_idx[blk * 128 + wave * 32 + row] = besti[r];
        }
    }
    #undef BUFP
}

// ---------------------------------------------------------------------------
// Gather codebook rows, write quantized NCHW (straight-through), accumulate loss.
// 2048 blocks x 256 thr, float4 I/O, 8 iters.
__global__ __launch_bounds__(256) void k_quant(const float* __restrict__ x,
                                               const float* __restrict__ ew,
                                               const int* __restrict__ idxv,
                                               float* __restrict__ out,
                                               float* __restrict__ loss_acc) {
    int t = threadIdx.x;
    int bid = blockIdx.x;
    float lsum = 0.0f;
    #pragma unroll
    for (int i = 0; i < 8; ++i) {
        unsigned f4 = (unsigned)bid * 256u + t + (unsigned)i * 524288u;  // < 4194304
        unsigned g = f4 * 4u;
        unsigned hw = g & 1023u;
        unsigned c = (g >> 10) & 255u;
        unsigned b = g >> 18;
        unsigned n = (b << 10) | hw;
        float4 xv = *reinterpret_cast<const float4*>(x + g);
        int i0 = idxv[n], i1 = idxv[n + 1], i2 = idxv[n + 2], i3 = idxv[n + 3];
        float q0 = ew[(size_t)i0 * DIMS + c];
        float q1 = ew[(size_t)i1 * DIMS + c];
        float q2 = ew[(size_t)i2 * DIMS + c];
        float q3 = ew[(size_t)i3 * DIMS + c];
        float d0 = q0 - xv.x, d1 = q1 - xv.y, d2 = q2 - xv.z, d3 = q3 - xv.w;
        float4 o;
        o.x = xv.x + d0; o.y = xv.y + d1; o.z = xv.z + d2; o.w = xv.w + d3;
        *reinterpret_cast<float4*>(out + OUT_Q_OFF + g) = o;
        lsum += d0 * d0 + d1 * d1 + d2 * d2 + d3 * d3;
    }
    #pragma unroll
    for (int off = 32; off > 0; off >>= 1) lsum += __shfl_down(lsum, off);
    if ((t & 63) == 0) atomicAdd(&loss_acc[bid & 63], lsum);
}

// ---------------------------------------------------------------------------
// Histogram of idx (LDS-local then global) + write idx as float output.
__global__ __launch_bounds__(256) void k_hist(const int* __restrict__ idxv,
                                              int* __restrict__ counts,
                                              float* __restrict__ out) {
    __shared__ int h[NCODE];
    int t = threadIdx.x;
    #pragma unroll
    for (int i = 0; i < 4; ++i) h[t + 256 * i] = 0;
    __syncthreads();
    int base = blockIdx.x * 1024;
    #pragma unroll
    for (int i = 0; i < 4; ++i) {
        int n = base + t + 256 * i;
        int id = idxv[n];
        out[OUT_IDX_OFF + n] = (float)id;
        atomicAdd(&h[id], 1);
    }
    __syncthreads();
    #pragma unroll
    for (int i = 0; i < 4; ++i) {
        int v = h[t + 256 * i];
        if (v) atomicAdd(&counts[t + 256 * i], v);
    }
}

// ---------------------------------------------------------------------------
// Perplexity + final loss.
__global__ __launch_bounds__(256) void k_final(const int* __restrict__ counts,
                                               const float* __restrict__ loss_acc,
                                               float* __restrict__ out) {
    int t = threadIdx.x;
    float s = 0.0f;
    #pragma unroll
    for (int i = 0; i < 4; ++i) {
        int cnt = counts[t + 256 * i];
        float p = (float)cnt * (1.0f / 65536.0f);
        s += p * logf(p + 1e-10f);
    }
    #pragma unroll
    for (int off = 32; off > 0; off >>= 1) s += __shfl_down(s, off);
    __shared__ float wsum[4];
    if ((t & 63) == 0) wsum[t >> 6] = s;
    __syncthreads();
    if (t == 0) {
        float S = wsum[0] + wsum[1] + wsum[2] + wsum[3];
        out[OUT_PERP_OFF] = expf(-S);
        float ls = 0.0f;
        for (int i = 0; i < 64; ++i) ls += loss_acc[i];
        out[0] = 0.25f * (ls * (1.0f / 16777216.0f));
    }
}

// ---------------------------------------------------------------------------
extern "C" void kernel_launch(void* const* d_in, const int* in_sizes, int n_in,
                              void* d_out, int out_size, void* d_ws, size_t ws_size,
                              hipStream_t stream) {
    const float* x = (const float*)d_in[0];    // [64,256,32,32]
    const float* ew = (const float*)d_in[1];   // [1024,256]
    float* out = (float*)d_out;
    float* ws = (float*)d_ws;

    float* loss_acc = ws;                      // 64 floats
    int* counts = (int*)(ws + 64);             // 1024 ints
    float* enorm = ws + 64 + 1024;             // 1024 floats
    int* idxv = (int*)(ws + 64 + 2048);        // 65536 ints

    // f16 hi/lo planes parked in the quantized out region (overwritten by k_quant later)
    f16* ehi = (f16*)(out + EHI_F32_OFF);
    f16* elo = (f16*)(out + ELO_F32_OFF);

    hipMemsetAsync(d_ws, 0, (64 + 1024) * sizeof(float), stream);

    k_esplit<<<256, 256, 0, stream>>>(ew, ehi, elo);
    k_enorm<<<NCODE, 64, 0, stream>>>(ew, enorm);
    k_argmin_mfma<<<512, 256, 0, stream>>>(x, ehi, elo, enorm, idxv);
    k_quant<<<2048, 256, 0, stream>>>(x, ew, idxv, out, loss_acc);
    k_hist<<<64, 256, 0, stream>>>(idxv, counts, out);
    k_final<<<1, 256, 0, stream>>>(counts, loss_acc, out);
}

// Round 5
// 200.400 us; speedup vs baseline: 1.3624x; 1.3624x over previous
//
#include <hip/hip_runtime.h>
#include <hip/hip_bf16.h>
#include <math.h>

typedef _Float16 f16;
typedef __attribute__((ext_vector_type(8))) _Float16 f16x8;
typedef __attribute__((ext_vector_type(16))) float f32x16;

// Problem constants
#define DIMS 256
#define NCODE 1024
#define NPTS 65536          // 64 * 32 * 32

// d_out layout (floats): [0]=loss, [1..16777217)=quantized NCHW (2^24 elems),
// [16777217]=perplexity, [16777218..16842754)=idx as float (65536)
#define OUT_Q_OFF 1
#define OUT_PERP_OFF 16777217
#define OUT_IDX_OFF 16777218

// E hi/lo f16 planes parked inside the (later overwritten) quantized out region.
#define EHI_F32_OFF 4
#define ELO_F32_OFF (4 + 131072)

#define ESTRIDE 264         // f16 per padded LDS row (528 B) — 0 bank conflicts measured
#define XSTRIDE 132         // fp32 per padded LDS row for X transpose chunks

// ---------------------------------------------------------------------------
// Fused E-prep: split E into f16 hi/lo planes + compute ||e||^2.
// One wave per codebook row. 256 blocks x 256 thr (4 waves).
__global__ __launch_bounds__(256) void k_eprep(const float* __restrict__ ew,
                                               f16* __restrict__ ehi,
                                               f16* __restrict__ elo,
                                               float* __restrict__ enorm) {
    int w = threadIdx.x >> 6;
    int l = threadIdx.x & 63;
    int row = blockIdx.x * 4 + w;
    float4 v = *reinterpret_cast<const float4*>(ew + (size_t)row * DIMS + l * 4);
    float vv[4] = {v.x, v.y, v.z, v.w};
    __align__(8) f16 hh[4];
    __align__(8) f16 ll[4];
    float s = 0.0f;
    #pragma unroll
    for (int e = 0; e < 4; ++e) {
        f16 h = (f16)vv[e];
        hh[e] = h;
        ll[e] = (f16)(vv[e] - (float)h);
        s += vv[e] * vv[e];
    }
    *reinterpret_cast<float2*>(ehi + (size_t)row * DIMS + l * 4) = *reinterpret_cast<float2*>(hh);
    *reinterpret_cast<float2*>(elo + (size_t)row * DIMS + l * 4) = *reinterpret_cast<float2*>(ll);
    #pragma unroll
    for (int off = 32; off > 0; off >>= 1) s += __shfl_down(s, off);
    if (l == 0) enorm[row] = s;
}

// ---------------------------------------------------------------------------
// MFMA argmin (round-3 proven structure, byte-identical).
// Block = 4 waves x 32 points = 128 points, grid = 512.
__global__ __launch_bounds__(256, 2) void k_argmin_mfma(const float* __restrict__ x,
                                                        const f16* __restrict__ ehi,
                                                        const f16* __restrict__ elo,
                                                        const float* __restrict__ enorm,
                                                        int* __restrict__ out_idx) {
    __shared__ __align__(16) char smem[2 * 32 * ESTRIDE * 2];   // 33792 B, unioned
    __shared__ float enorm_lds[NCODE];
    float* Xs = (float*)smem;                   // phase 1: [64 dims][XSTRIDE] fp32
    f16* EHI = (f16*)smem;                      // phase 2: [32][ESTRIDE]
    f16* ELO = (f16*)(smem + 32 * ESTRIDE * 2);

    const int t = threadIdx.x;
    const int wave = t >> 6;
    const int lane = t & 63;
    const int lrow = lane & 31;
    const int lhalf = lane >> 5;

    const int blk = blockIdx.x;                 // 0..511
    const int b = blk >> 3;
    const int hw0 = (blk & 7) << 7;
    const float* xb = x + (size_t)b * (DIMS * 1024) + hw0;

    // stage enorm into LDS (covered by first barrier below)
    #pragma unroll
    for (int i = 0; i < 4; ++i) enorm_lds[t + 256 * i] = enorm[t + 256 * i];

    // ---- Phase 1: build split-f16 A fragments for this wave's 32 points ----
    f16x8 ahi[16], alo[16];
    #pragma unroll
    for (int dc = 0; dc < 4; ++dc) {
        __syncthreads();
        #pragma unroll
        for (int i = 0; i < 8; ++i) {
            int d = (t >> 5) + 8 * i;           // 0..63
            int p4 = (t & 31) * 4;              // 0..124
            float4 v = *reinterpret_cast<const float4*>(xb + (size_t)(dc * 64 + d) * 1024 + p4);
            *reinterpret_cast<float4*>(&Xs[d * XSTRIDE + p4]) = v;
        }
        __syncthreads();
        int p = wave * 32 + lrow;
        #pragma unroll
        for (int kcl = 0; kcl < 4; ++kcl) {
            f16x8 h, l;
            #pragma unroll
            for (int e = 0; e < 8; ++e) {
                float xv = Xs[(kcl * 16 + lhalf * 8 + e) * XSTRIDE + p];
                f16 hi = (f16)xv;
                h[e] = hi;
                l[e] = (f16)(xv - (float)hi);
            }
            ahi[dc * 4 + kcl] = h;
            alo[dc * 4 + kcl] = l;
        }
    }

    // ---- Phase 2: loop code tiles ----
    float bestv[16];
    int besti[16];
    #pragma unroll
    for (int r = 0; r < 16; ++r) { bestv[r] = 3.4e38f; besti[r] = 0; }

    for (int rd = 0; rd < 32; ++rd) {
        const int code0 = rd * 32;
        __syncthreads();
        // stage 32 codes x 256 f16 for both planes
        #pragma unroll
        for (int j = 0; j < 4; ++j) {
            int q = t + 256 * j;                // 0..1023
            int row = q >> 5;
            int cc = q & 31;
            const f16* sh = ehi + (size_t)(code0 + row) * DIMS + cc * 8;
            const f16* sl = elo + (size_t)(code0 + row) * DIMS + cc * 8;
            float4 vh = *reinterpret_cast<const float4*>(sh);
            float4 vl = *reinterpret_cast<const float4*>(sl);
            *reinterpret_cast<float4*>((char*)EHI + row * (ESTRIDE * 2) + cc * 16) = vh;
            *reinterpret_cast<float4*>((char*)ELO + row * (ESTRIDE * 2) + cc * 16) = vl;
        }
        __syncthreads();

        f32x16 acc;
        #pragma unroll
        for (int r = 0; r < 16; ++r) acc[r] = 0.0f;

        #pragma unroll
        for (int kc = 0; kc < 16; ++kc) {
            f16x8 bh = *reinterpret_cast<const f16x8*>(
                (const char*)EHI + lrow * (ESTRIDE * 2) + (kc * 2 + lhalf) * 16);
            f16x8 bl = *reinterpret_cast<const f16x8*>(
                (const char*)ELO + lrow * (ESTRIDE * 2) + (kc * 2 + lhalf) * 16);
            acc = __builtin_amdgcn_mfma_f32_32x32x16_f16(ahi[kc], bh, acc, 0, 0, 0);
            acc = __builtin_amdgcn_mfma_f32_32x32x16_f16(ahi[kc], bl, acc, 0, 0, 0);
            acc = __builtin_amdgcn_mfma_f32_32x32x16_f16(alo[kc], bh, acc, 0, 0, 0);
        }

        // argmin update: s = ||e||^2 - 2*dot (||x||^2 dropped, constant per point)
        float en = enorm_lds[code0 + lrow];
        int cw = code0 + lrow;
        #pragma unroll
        for (int r = 0; r < 16; ++r) {
            float s = fmaf(-2.0f, acc[r], en);
            if (s < bestv[r]) { bestv[r] = s; besti[r] = cw; }   // strict <: lowest code wins
        }
    }

    // ---- cross-lane argmin reduce over the 32 codes dimension (lrow) ----
    #pragma unroll
    for (int off = 1; off <= 16; off <<= 1) {
        #pragma unroll
        for (int r = 0; r < 16; ++r) {
            float ov = __shfl_xor(bestv[r], off);
            int oi = __shfl_xor(besti[r], off);
            if (ov < bestv[r] || (ov == bestv[r] && oi < besti[r])) {
                bestv[r] = ov;
                besti[r] = oi;
            }
        }
    }
    if (lrow == 0) {
        #pragma unroll
        for (int r = 0; r < 16; ++r) {
            int row = (r & 3) + 8 * (r >> 2) + 4 * lhalf;   // C/D row mapping
            out_idx[blk * 128 + wave * 32 + row] = besti[r];
        }
    }
}

// ---------------------------------------------------------------------------
// Tiled quantize: block = 64 points, gather the needed E rows ONCE into LDS
// (coalesced row reads), then stream x/out fully coalesced.
// grid 1024, 512 threads. LDS [64][258] fp32 (stride 258: float2-aligned,
// 2-way-free banks on scalar reads).
#define QSTRIDE 258
__global__ __launch_bounds__(512) void k_quant(const float* __restrict__ x,
                                               const float* __restrict__ ew,
                                               const int* __restrict__ idxv,
                                               float* __restrict__ out,
                                               float* __restrict__ loss_acc) {
    __shared__ float Eq[64 * QSTRIDE];          // 66048 B
    __shared__ int ids[64];
    const int t = threadIdx.x;
    const int blk = blockIdx.x;                 // 0..1023
    const int b = blk >> 4;
    const int hw0 = (blk & 15) << 6;

    if (t < 64) ids[t] = idxv[(b << 10) + hw0 + t];
    __syncthreads();

    // stage 64 gathered E rows: 4096 float4 / 512 thr = 8 iters, coalesced per row
    #pragma unroll
    for (int i = 0; i < 8; ++i) {
        int f = i * 512 + t;                    // float4 id in [64][64]
        int row = f >> 6;
        int c4 = f & 63;
        float4 v = *reinterpret_cast<const float4*>(ew + (size_t)ids[row] * DIMS + c4 * 4);
        float2 lo2 = {v.x, v.y};
        float2 hi2 = {v.z, v.w};
        *reinterpret_cast<float2*>(&Eq[row * QSTRIDE + c4 * 4]) = lo2;
        *reinterpret_cast<float2*>(&Eq[row * QSTRIDE + c4 * 4 + 2]) = hi2;
    }
    __syncthreads();

    const int p = t & 63;                       // point within tile
    const int c0 = t >> 6;                      // 0..7
    float lsum = 0.0f;
    #pragma unroll
    for (int k = 0; k < 32; ++k) {
        int c = k * 8 + c0;
        unsigned g = ((unsigned)b << 18) | ((unsigned)c << 10) | (unsigned)(hw0 + p);
        float xv = x[g];
        float q = Eq[p * QSTRIDE + c];
        float d = q - xv;
        out[OUT_Q_OFF + g] = xv + d;            // mimic reference x + (q - x)
        lsum += d * d;
    }
    #pragma unroll
    for (int off = 32; off > 0; off >>= 1) lsum += __shfl_down(lsum, off);
    if ((t & 63) == 0) atomicAdd(&loss_acc[blk & 63], lsum);
}

// ---------------------------------------------------------------------------
// Histogram of idx (LDS-local then global) + write idx as float output.
__global__ __launch_bounds__(256) void k_hist(const int* __restrict__ idxv,
                                              int* __restrict__ counts,
                                              float* __restrict__ out) {
    __shared__ int h[NCODE];
    int t = threadIdx.x;
    #pragma unroll
    for (int i = 0; i < 4; ++i) h[t + 256 * i] = 0;
    __syncthreads();
    int base = blockIdx.x * 1024;
    #pragma unroll
    for (int i = 0; i < 4; ++i) {
        int n = base + t + 256 * i;
        int id = idxv[n];
        out[OUT_IDX_OFF + n] = (float)id;
        atomicAdd(&h[id], 1);
    }
    __syncthreads();
    #pragma unroll
    for (int i = 0; i < 4; ++i) {
        int v = h[t + 256 * i];
        if (v) atomicAdd(&counts[t + 256 * i], v);
    }
}

// ---------------------------------------------------------------------------
// Perplexity + final loss.
__global__ __launch_bounds__(256) void k_final(const int* __restrict__ counts,
                                               const float* __restrict__ loss_acc,
                                               float* __restrict__ out) {
    int t = threadIdx.x;
    float s = 0.0f;
    #pragma unroll
    for (int i = 0; i < 4; ++i) {
        int cnt = counts[t + 256 * i];
        float p = (float)cnt * (1.0f / 65536.0f);
        s += p * logf(p + 1e-10f);
    }
    #pragma unroll
    for (int off = 32; off > 0; off >>= 1) s += __shfl_down(s, off);
    __shared__ float wsum[4];
    if ((t & 63) == 0) wsum[t >> 6] = s;
    __syncthreads();
    if (t == 0) {
        float S = wsum[0] + wsum[1] + wsum[2] + wsum[3];
        out[OUT_PERP_OFF] = expf(-S);
        float ls = 0.0f;
        for (int i = 0; i < 64; ++i) ls += loss_acc[i];
        out[0] = 0.25f * (ls * (1.0f / 16777216.0f));
    }
}

// ---------------------------------------------------------------------------
extern "C" void kernel_launch(void* const* d_in, const int* in_sizes, int n_in,
                              void* d_out, int out_size, void* d_ws, size_t ws_size,
                              hipStream_t stream) {
    const float* x = (const float*)d_in[0];    // [64,256,32,32]
    const float* ew = (const float*)d_in[1];   // [1024,256]
    float* out = (float*)d_out;
    float* ws = (float*)d_ws;

    float* loss_acc = ws;                      // 64 floats
    int* counts = (int*)(ws + 64);             // 1024 ints
    float* enorm = ws + 64 + 1024;             // 1024 floats
    int* idxv = (int*)(ws + 64 + 2048);        // 65536 ints

    // f16 hi/lo planes parked in the quantized out region (overwritten by k_quant later)
    f16* ehi = (f16*)(out + EHI_F32_OFF);
    f16* elo = (f16*)(out + ELO_F32_OFF);

    hipMemsetAsync(d_ws, 0, (64 + 1024) * sizeof(float), stream);

    k_eprep<<<256, 256, 0, stream>>>(ew, ehi, elo, enorm);
    k_argmin_mfma<<<512, 256, 0, stream>>>(x, ehi, elo, enorm, idxv);
    k_quant<<<1024, 512, 0, stream>>>(x, ew, idxv, out, loss_acc);
    k_hist<<<64, 256, 0, stream>>>(idxv, counts, out);
    k_final<<<1, 256, 0, stream>>>(counts, loss_acc, out);
}

// Round 6
// 178.400 us; speedup vs baseline: 1.5305x; 1.1233x over previous
//
#include <hip/hip_runtime.h>
#include <hip/hip_bf16.h>
#include <math.h>

typedef _Float16 f16;
typedef __attribute__((ext_vector_type(8))) _Float16 f16x8;
typedef __attribute__((ext_vector_type(16))) float f32x16;

// Problem constants
#define DIMS 256
#define NCODE 1024
#define NPTS 65536          // 64 * 32 * 32

// d_out layout (floats): [0]=loss, [1..16777217)=quantized NCHW (2^24 elems),
// [16777217]=perplexity, [16777218..16842754)=idx as float (65536)
#define OUT_Q_OFF 1
#define OUT_PERP_OFF 16777217
#define OUT_IDX_OFF 16777218

// E hi/lo f16 planes parked inside the (later overwritten) quantized out region.
// Stored in STAGED order: per 32-code tile (16384 B), row=code&31 (512 B),
// granule g=dim>>3 placed at position g^(row&7)  ->  global_load_lds copies
// linearly and the LDS image is read conflict-minimal by ds_read_b128.
#define EHI_F32_OFF 4
#define ELO_F32_OFF (4 + 131072)
#define TILE_BYTES 16384

#define XSTRIDE 132         // fp32 per padded LDS row for X transpose chunks

// Direct HBM/L2 -> LDS copy, 16 B per lane; LDS dest = uniform base + lane*16.
__device__ __forceinline__ void gload_lds16(const void* g, void* l) {
    __builtin_amdgcn_global_load_lds(
        (const __attribute__((address_space(1))) unsigned int*)g,
        (__attribute__((address_space(3))) unsigned int*)l, 16, 0, 0);
}

// ---------------------------------------------------------------------------
// Fused E-prep: split E into f16 hi/lo planes (staged/swizzled order) + ||e||^2.
// One wave per codebook row. 256 blocks x 256 thr (4 waves).
__global__ __launch_bounds__(256) void k_eprep(const float* __restrict__ ew,
                                               char* __restrict__ ehi,
                                               char* __restrict__ elo,
                                               float* __restrict__ enorm) {
    int w = threadIdx.x >> 6;
    int l = threadIdx.x & 63;
    int row = blockIdx.x * 4 + w;
    float4 v = *reinterpret_cast<const float4*>(ew + (size_t)row * DIMS + l * 4);
    float vv[4] = {v.x, v.y, v.z, v.w};
    __align__(8) f16 hh[4];
    __align__(8) f16 ll[4];
    float s = 0.0f;
    #pragma unroll
    for (int e = 0; e < 4; ++e) {
        f16 h = (f16)vv[e];
        hh[e] = h;
        ll[e] = (f16)(vv[e] - (float)h);
        s += vv[e] * vv[e];
    }
    // lane l covers dims 4l..4l+3 -> granule g = l>>1, low/high half by l&1
    size_t off = (size_t)(row >> 5) * TILE_BYTES + (size_t)(row & 31) * 512
               + (size_t)((((l >> 1) ^ (row & 7)) << 4) + ((l & 1) << 3));
    *reinterpret_cast<float2*>(ehi + off) = *reinterpret_cast<float2*>(hh);
    *reinterpret_cast<float2*>(elo + off) = *reinterpret_cast<float2*>(ll);
    #pragma unroll
    for (int off2 = 32; off2 > 0; off2 >>= 1) s += __shfl_down(s, off2);
    if (l == 0) enorm[row] = s;
}

// ---------------------------------------------------------------------------
// MFMA argmin, double-buffered E via global_load_lds prefetch (1 barrier/round,
// zero staging VGPRs). Block = 4 waves x 32 points = 128 points, grid = 512.
__global__ __launch_bounds__(256, 2) void k_argmin_mfma(const float* __restrict__ x,
                                                        const char* __restrict__ ehi,
                                                        const char* __restrict__ elo,
                                                        const float* __restrict__ enorm,
                                                        int* __restrict__ out_idx) {
    __shared__ __align__(16) char smem[2 * 2 * TILE_BYTES];   // [buf][EH|EL] 65536 B
    __shared__ float enorm_lds[NCODE];
    float* Xs = (float*)smem;                   // phase 1 reuse: [64][XSTRIDE] fp32 (33792 B)

    const int t = threadIdx.x;
    const int wave = t >> 6;
    const int lane = t & 63;
    const int lrow = lane & 31;
    const int lhalf = lane >> 5;

    const int blk = blockIdx.x;                 // 0..511
    const int b = blk >> 3;
    const int hw0 = (blk & 7) << 7;
    const float* xb = x + (size_t)b * (DIMS * 1024) + hw0;

    // stage enorm into LDS (covered by first barrier below)
    #pragma unroll
    for (int i = 0; i < 4; ++i) enorm_lds[t + 256 * i] = enorm[t + 256 * i];

    // ---- Phase 1: build split-f16 A fragments for this wave's 32 points ----
    f16x8 ahi[16], alo[16];
    #pragma unroll
    for (int dc = 0; dc < 4; ++dc) {
        __syncthreads();
        #pragma unroll
        for (int i = 0; i < 8; ++i) {
            int d = (t >> 5) + 8 * i;           // 0..63
            int p4 = (t & 31) * 4;              // 0..124
            float4 v = *reinterpret_cast<const float4*>(xb + (size_t)(dc * 64 + d) * 1024 + p4);
            *reinterpret_cast<float4*>(&Xs[d * XSTRIDE + p4]) = v;
        }
        __syncthreads();
        int p = wave * 32 + lrow;
        #pragma unroll
        for (int kcl = 0; kcl < 4; ++kcl) {
            f16x8 h, l;
            #pragma unroll
            for (int e = 0; e < 8; ++e) {
                float xv = Xs[(kcl * 16 + lhalf * 8 + e) * XSTRIDE + p];
                f16 hi = (f16)xv;
                h[e] = hi;
                l[e] = (f16)(xv - (float)hi);
            }
            ahi[dc * 4 + kcl] = h;
            alo[dc * 4 + kcl] = l;
        }
    }
    __syncthreads();    // all waves done reading Xs before buf0 staging lands

    // ---- staging assignment: waves 0,1 -> EH plane; waves 2,3 -> EL plane ----
    const char* gplane = (wave >> 1) ? elo : ehi;
    const int pl_off = (wave >> 1) * TILE_BYTES;     // within a buffer
    const int woff = (wave & 1) * 8192;              // half of a 16 KB plane

    // ---- Prologue: stage tile 0 into buffer 0 ----
    #pragma unroll
    for (int i = 0; i < 8; ++i) {
        int off = woff + i * 1024;
        gload_lds16(gplane + off + lane * 16, smem + pl_off + off);
    }
    __syncthreads();    // implicit vmcnt(0): buf0 ready

    // ---- Main loop: 32 rounds of 32 codes, 1 barrier per round ----
    float bestv[16];
    int besti[16];
    #pragma unroll
    for (int r = 0; r < 16; ++r) { bestv[r] = 3.4e38f; besti[r] = 0; }

    int cur = 0;
    for (int rd = 0; rd < 32; ++rd) {
        // issue next tile's HBM->LDS copies into the other buffer (no regs held)
        if (rd + 1 < 32) {
            const char* gp = gplane + (size_t)(rd + 1) * TILE_BYTES;
            char* lp = smem + (cur ^ 1) * (2 * TILE_BYTES) + pl_off;
            #pragma unroll
            for (int i = 0; i < 8; ++i) {
                int off = woff + i * 1024;
                gload_lds16(gp + off + lane * 16, lp + off);
            }
        }

        // compute current buffer
        const char* EHb = smem + cur * (2 * TILE_BYTES);
        const char* ELb = EHb + TILE_BYTES;
        f32x16 acc;
        #pragma unroll
        for (int r = 0; r < 16; ++r) acc[r] = 0.0f;

        #pragma unroll
        for (int kc = 0; kc < 16; ++kc) {
            int g = kc * 2 + lhalf;
            int ra = lrow * 512 + ((g ^ (lrow & 7)) << 4);   // swizzled read addr
            f16x8 bh = *reinterpret_cast<const f16x8*>(EHb + ra);
            f16x8 bl = *reinterpret_cast<const f16x8*>(ELb + ra);
            acc = __builtin_amdgcn_mfma_f32_32x32x16_f16(ahi[kc], bh, acc, 0, 0, 0);
            acc = __builtin_amdgcn_mfma_f32_32x32x16_f16(ahi[kc], bl, acc, 0, 0, 0);
            acc = __builtin_amdgcn_mfma_f32_32x32x16_f16(alo[kc], bh, acc, 0, 0, 0);
        }

        // argmin update: s = ||e||^2 - 2*dot (||x||^2 dropped, constant per point)
        const int code0 = rd * 32;
        float en = enorm_lds[code0 + lrow];
        int cw = code0 + lrow;
        #pragma unroll
        for (int r = 0; r < 16; ++r) {
            float s = fmaf(-2.0f, acc[r], en);
            if (s < bestv[r]) { bestv[r] = s; besti[r] = cw; }   // strict <: lowest code wins
        }

        __syncthreads();    // implicit vmcnt(0): next buffer ready; all reads of cur done
        cur ^= 1;
    }

    // ---- cross-lane argmin reduce over the 32 codes dimension (lrow) ----
    #pragma unroll
    for (int off = 1; off <= 16; off <<= 1) {
        #pragma unroll
        for (int r = 0; r < 16; ++r) {
            float ov = __shfl_xor(bestv[r], off);
            int oi = __shfl_xor(besti[r], off);
            if (ov < bestv[r] || (ov == bestv[r] && oi < besti[r])) {
                bestv[r] = ov;
                besti[r] = oi;
            }
        }
    }
    if (lrow == 0) {
        #pragma unroll
        for (int r = 0; r < 16; ++r) {
            int row = (r & 3) + 8 * (r >> 2) + 4 * lhalf;   // C/D row mapping
            out_idx[blk * 128 + wave * 32 + row] = besti[r];
        }
    }
}

// ---------------------------------------------------------------------------
// Tiled quantize: block = 64 points, gather the needed E rows ONCE into LDS
// (coalesced row reads), then stream x/out fully coalesced.
// grid 1024, 512 threads. LDS [64][258] fp32.
#define QSTRIDE 258
__global__ __launch_bounds__(512) void k_quant(const float* __restrict__ x,
                                               const float* __restrict__ ew,
                                               const int* __restrict__ idxv,
                                               float* __restrict__ out,
                                               float* __restrict__ loss_acc) {
    __shared__ float Eq[64 * QSTRIDE];          // 66048 B
    __shared__ int ids[64];
    const int t = threadIdx.x;
    const int blk = blockIdx.x;                 // 0..1023
    const int b = blk >> 4;
    const int hw0 = (blk & 15) << 6;

    if (t < 64) ids[t] = idxv[(b << 10) + hw0 + t];
    __syncthreads();

    // stage 64 gathered E rows: 4096 float4 / 512 thr = 8 iters, coalesced per row
    #pragma unroll
    for (int i = 0; i < 8; ++i) {
        int f = i * 512 + t;                    // float4 id in [64][64]
        int row = f >> 6;
        int c4 = f & 63;
        float4 v = *reinterpret_cast<const float4*>(ew + (size_t)ids[row] * DIMS + c4 * 4);
        float2 lo2 = {v.x, v.y};
        float2 hi2 = {v.z, v.w};
        *reinterpret_cast<float2*>(&Eq[row * QSTRIDE + c4 * 4]) = lo2;
        *reinterpret_cast<float2*>(&Eq[row * QSTRIDE + c4 * 4 + 2]) = hi2;
    }
    __syncthreads();

    const int p = t & 63;                       // point within tile
    const int c0 = t >> 6;                      // 0..7
    float lsum = 0.0f;
    #pragma unroll
    for (int k = 0; k < 32; ++k) {
        int c = k * 8 + c0;
        unsigned g = ((unsigned)b << 18) | ((unsigned)c << 10) | (unsigned)(hw0 + p);
        float xv = x[g];
        float q = Eq[p * QSTRIDE + c];
        float d = q - xv;
        out[OUT_Q_OFF + g] = xv + d;            // mimic reference x + (q - x)
        lsum += d * d;
    }
    #pragma unroll
    for (int off = 32; off > 0; off >>= 1) lsum += __shfl_down(lsum, off);
    if ((t & 63) == 0) atomicAdd(&loss_acc[blk & 63], lsum);
}

// ---------------------------------------------------------------------------
// Histogram of idx (LDS-local then global) + write idx as float output.
__global__ __launch_bounds__(256) void k_hist(const int* __restrict__ idxv,
                                              int* __restrict__ counts,
                                              float* __restrict__ out) {
    __shared__ int h[NCODE];
    int t = threadIdx.x;
    #pragma unroll
    for (int i = 0; i < 4; ++i) h[t + 256 * i] = 0;
    __syncthreads();
    int base = blockIdx.x * 1024;
    #pragma unroll
    for (int i = 0; i < 4; ++i) {
        int n = base + t + 256 * i;
        int id = idxv[n];
        out[OUT_IDX_OFF + n] = (float)id;
        atomicAdd(&h[id], 1);
    }
    __syncthreads();
    #pragma unroll
    for (int i = 0; i < 4; ++i) {
        int v = h[t + 256 * i];
        if (v) atomicAdd(&counts[t + 256 * i], v);
    }
}

// ---------------------------------------------------------------------------
// Perplexity + final loss.
__global__ __launch_bounds__(256) void k_final(const int* __restrict__ counts,
                                               const float* __restrict__ loss_acc,
                                               float* __restrict__ out) {
    int t = threadIdx.x;
    float s = 0.0f;
    #pragma unroll
    for (int i = 0; i < 4; ++i) {
        int cnt = counts[t + 256 * i];
        float p = (float)cnt * (1.0f / 65536.0f);
        s += p * logf(p + 1e-10f);
    }
    #pragma unroll
    for (int off = 32; off > 0; off >>= 1) s += __shfl_down(s, off);
    __shared__ float wsum[4];
    if ((t & 63) == 0) wsum[t >> 6] = s;
    __syncthreads();
    if (t == 0) {
        float S = wsum[0] + wsum[1] + wsum[2] + wsum[3];
        out[OUT_PERP_OFF] = expf(-S);
        float ls = 0.0f;
        for (int i = 0; i < 64; ++i) ls += loss_acc[i];
        out[0] = 0.25f * (ls * (1.0f / 16777216.0f));
    }
}

// ---------------------------------------------------------------------------
extern "C" void kernel_launch(void* const* d_in, const int* in_sizes, int n_in,
                              void* d_out, int out_size, void* d_ws, size_t ws_size,
                              hipStream_t stream) {
    const float* x = (const float*)d_in[0];    // [64,256,32,32]
    const float* ew = (const float*)d_in[1];   // [1024,256]
    float* out = (float*)d_out;
    float* ws = (float*)d_ws;

    float* loss_acc = ws;                      // 64 floats
    int* counts = (int*)(ws + 64);             // 1024 ints
    float* enorm = ws + 64 + 1024;             // 1024 floats
    int* idxv = (int*)(ws + 64 + 2048);        // 65536 ints

    // f16 hi/lo staged planes parked in the quantized out region (overwritten by k_quant)
    char* ehi = (char*)(out + EHI_F32_OFF);
    char* elo = (char*)(out + ELO_F32_OFF);

    hipMemsetAsync(d_ws, 0, (64 + 1024) * sizeof(float), stream);

    k_eprep<<<256, 256, 0, stream>>>(ew, ehi, elo, enorm);
    k_argmin_mfma<<<512, 256, 0, stream>>>(x, ehi, elo, enorm, idxv);
    k_quant<<<1024, 512, 0, stream>>>(x, ew, idxv, out, loss_acc);
    k_hist<<<64, 256, 0, stream>>>(idxv, counts, out);
    k_final<<<1, 256, 0, stream>>>(counts, loss_acc, out);
}